// Round 1
// baseline (1611.363 us; speedup 1.0000x reference)
//
#include <hip/hip_runtime.h>
#include <hip/hip_bf16.h>

#define BT 2048
#define VOC 32000
#define IGN (-100)

typedef __attribute__((ext_vector_type(4))) float f32x4;
typedef __attribute__((ext_vector_type(8))) short s16x8;
typedef __attribute__((ext_vector_type(4))) unsigned int u32x4;

__device__ __forceinline__ unsigned short f2bf(float f) {
    union { __hip_bfloat16 h; unsigned short u; } c;
    c.h = __float2bfloat16(f);
    return c.u;
}
__device__ __forceinline__ float bf2f(unsigned short u) {
    union { unsigned int u; float f; } c;
    c.u = ((unsigned int)u) << 16;
    return c.f;
}
__device__ __forceinline__ unsigned int pk2(float a, float b) {
    return (unsigned int)f2bf(a) | ((unsigned int)f2bf(b) << 16);
}

// ---------------------------------------------------------------------------
// GEMM: C[m,v] = sum_k A[m,k] * W[v,k]   (A: M x K row-major, W: V x K row-major)
// M = 2048 fixed, N = VOC = 32000, K in {2048, 4096}. Output bf16 logits.
// 128x128 tile, BK=64, 256 threads (4 waves, 2x2), mfma_f32_16x16x32_bf16.
// fp32 global -> reg -> convert bf16 -> XOR-swizzled LDS, double buffered.
// ---------------------------------------------------------------------------
__global__ __launch_bounds__(256, 2)
void gemm_bf16(const float* __restrict__ A, const float* __restrict__ W,
               unsigned short* __restrict__ C, int K) {
    const int bid = blockIdx.x;
    const int mt = bid & 15;     // 2048/128 = 16 row tiles (m-inner for W-tile L2 reuse)
    const int nt = bid >> 4;     // 0..249
    const int tid = threadIdx.x;
    const int lane = tid & 63;
    const int wave = tid >> 6;
    const int wm = (wave >> 1) << 6;   // wave row origin in tile
    const int wn = (wave & 1) << 6;    // wave col origin in tile

    __shared__ unsigned short lds[2][2][128 * 64];  // [buf][A=0/B=1][row*64 + k]

    f32x4 acc[4][4];
    #pragma unroll
    for (int m = 0; m < 4; ++m)
        #pragma unroll
        for (int n = 0; n < 4; ++n)
            acc[m][n] = (f32x4){0.f, 0.f, 0.f, 0.f};

    const float* Ab = A + (size_t)(mt * 128) * K;
    const float* Wb = W + (size_t)(nt * 128) * K;
    const int nsteps = K >> 6;

    f32x4 ra[4][2], rb[4][2];
    int rrow[4], rk16[4];
    #pragma unroll
    for (int it = 0; it < 4; ++it) {
        int idx = it * 256 + tid;    // 0..1023 granules of 8 elements
        rrow[it] = idx >> 3;         // 0..127
        rk16[it] = idx & 7;          // 16B granule within BK=64 row
    }

    auto load_regs = [&](int step) {
        const int kb = step << 6;
        #pragma unroll
        for (int it = 0; it < 4; ++it) {
            const float* pa = Ab + (size_t)rrow[it] * K + kb + rk16[it] * 8;
            const float* pw = Wb + (size_t)rrow[it] * K + kb + rk16[it] * 8;
            ra[it][0] = *(const f32x4*)pa;
            ra[it][1] = *(const f32x4*)(pa + 4);
            rb[it][0] = *(const f32x4*)pw;
            rb[it][1] = *(const f32x4*)(pw + 4);
        }
    };

    auto write_lds = [&](int buf) {
        #pragma unroll
        for (int it = 0; it < 4; ++it) {
            const int row = rrow[it];
            const int sw = rk16[it] ^ (row & 7);   // XOR swizzle on 16B granules
            const int off = row * 64 + sw * 8;
            u32x4 pa, pw;
            pa[0] = pk2(ra[it][0][0], ra[it][0][1]);
            pa[1] = pk2(ra[it][0][2], ra[it][0][3]);
            pa[2] = pk2(ra[it][1][0], ra[it][1][1]);
            pa[3] = pk2(ra[it][1][2], ra[it][1][3]);
            pw[0] = pk2(rb[it][0][0], rb[it][0][1]);
            pw[1] = pk2(rb[it][0][2], rb[it][0][3]);
            pw[2] = pk2(rb[it][1][0], rb[it][1][1]);
            pw[3] = pk2(rb[it][1][2], rb[it][1][3]);
            *(u32x4*)&lds[buf][0][off] = pa;
            *(u32x4*)&lds[buf][1][off] = pw;
        }
    };

    auto compute = [&](int buf) {
        #pragma unroll
        for (int ks = 0; ks < 2; ++ks) {
            const int g = ks * 4 + (lane >> 4);   // 16B granule index for this frag
            const int rsel = lane & 15;
            s16x8 af[4], bw[4];
            #pragma unroll
            for (int m = 0; m < 4; ++m) {
                int row = wm + m * 16 + rsel;
                af[m] = *(const s16x8*)&lds[buf][0][row * 64 + ((g ^ (row & 7)) * 8)];
            }
            #pragma unroll
            for (int n = 0; n < 4; ++n) {
                int row = wn + n * 16 + rsel;
                bw[n] = *(const s16x8*)&lds[buf][1][row * 64 + ((g ^ (row & 7)) * 8)];
            }
            #pragma unroll
            for (int m = 0; m < 4; ++m)
                #pragma unroll
                for (int n = 0; n < 4; ++n)
                    acc[m][n] = __builtin_amdgcn_mfma_f32_16x16x32_bf16(
                        af[m], bw[n], acc[m][n], 0, 0, 0);
        }
    };

    load_regs(0);
    write_lds(0);
    __syncthreads();
    for (int s = 0; s < nsteps; ++s) {
        if (s + 1 < nsteps) load_regs(s + 1);
        compute(s & 1);
        if (s + 1 < nsteps) write_lds((s + 1) & 1);
        __syncthreads();
    }

    // epilogue: C/D layout col = lane&15, row = (lane>>4)*4 + reg
    const int colb = nt * 128 + wn + (lane & 15);
    const int rowb = mt * 128 + wm + ((lane >> 4) << 2);
    #pragma unroll
    for (int m = 0; m < 4; ++m)
        #pragma unroll
        for (int n = 0; n < 4; ++n) {
            #pragma unroll
            for (int j = 0; j < 4; ++j) {
                int r = rowb + m * 16 + j;
                int c = colb + n * 16;
                C[(size_t)r * VOC + c] = f2bf(acc[m][n][j]);
            }
        }
}

// ---------------------------------------------------------------------------
// count kernel: n_non_ignore -> 1/n (or 0), and zero d_out (graph-replay safe)
// ---------------------------------------------------------------------------
__global__ void count_kernel(const int* __restrict__ label,
                             float* __restrict__ invn, float* __restrict__ out) {
    int tid = threadIdx.x;
    int c = 0;
    for (int i = tid; i < BT; i += 256) c += (label[i] != IGN) ? 1 : 0;
    #pragma unroll
    for (int o = 32; o > 0; o >>= 1) c += __shfl_xor(c, o);
    __shared__ int red[4];
    if ((tid & 63) == 0) red[tid >> 6] = c;
    __syncthreads();
    if (tid == 0) {
        int n = red[0] + red[1] + red[2] + red[3];
        invn[0] = (n > 0) ? (1.0f / (float)n) : 0.0f;
        out[0] = 0.0f;
    }
}

// ---------------------------------------------------------------------------
// JSD kernel: one block per token. 3 passes over both logit rows (bf16, from ws):
//   1) row max (p and q)   2) sum exp -> lse   3) JSD terms -> block sum -> atomic
// ---------------------------------------------------------------------------
__global__ __launch_bounds__(1024)
void jsd_kernel(const unsigned short* __restrict__ TL, const unsigned short* __restrict__ SL,
                const int* __restrict__ label, const float* __restrict__ invn,
                float* __restrict__ out) {
    const int b = blockIdx.x;
    const int tid = threadIdx.x;
    const unsigned short* tl = TL + (size_t)b * VOC;
    const unsigned short* sl = SL + (size_t)b * VOC;
    __shared__ float redA[16], redB[16];

    // pass 1: max
    float mp = -1e30f, mq = -1e30f;
    for (int i = tid; i < VOC / 8; i += 1024) {
        s16x8 vt = *(const s16x8*)(tl + i * 8);
        s16x8 vs = *(const s16x8*)(sl + i * 8);
        #pragma unroll
        for (int j = 0; j < 8; ++j) {
            mp = fmaxf(mp, bf2f((unsigned short)vt[j]));
            mq = fmaxf(mq, bf2f((unsigned short)vs[j]));
        }
    }
    #pragma unroll
    for (int o = 32; o > 0; o >>= 1) {
        mp = fmaxf(mp, __shfl_xor(mp, o));
        mq = fmaxf(mq, __shfl_xor(mq, o));
    }
    if ((tid & 63) == 0) { redA[tid >> 6] = mp; redB[tid >> 6] = mq; }
    __syncthreads();
    if (tid == 0) {
        float a = redA[0], c = redB[0];
        for (int w = 1; w < 16; ++w) { a = fmaxf(a, redA[w]); c = fmaxf(c, redB[w]); }
        redA[0] = a; redB[0] = c;
    }
    __syncthreads();
    mp = redA[0]; mq = redB[0];
    __syncthreads();

    // pass 2: sum exp
    float sp = 0.f, sq = 0.f;
    for (int i = tid; i < VOC / 8; i += 1024) {
        s16x8 vt = *(const s16x8*)(tl + i * 8);
        s16x8 vs = *(const s16x8*)(sl + i * 8);
        #pragma unroll
        for (int j = 0; j < 8; ++j) {
            sp += __expf(bf2f((unsigned short)vt[j]) - mp);
            sq += __expf(bf2f((unsigned short)vs[j]) - mq);
        }
    }
    #pragma unroll
    for (int o = 32; o > 0; o >>= 1) {
        sp += __shfl_xor(sp, o);
        sq += __shfl_xor(sq, o);
    }
    if ((tid & 63) == 0) { redA[tid >> 6] = sp; redB[tid >> 6] = sq; }
    __syncthreads();
    if (tid == 0) {
        float a = 0.f, c = 0.f;
        for (int w = 0; w < 16; ++w) { a += redA[w]; c += redB[w]; }
        redA[0] = a; redB[0] = c;
    }
    __syncthreads();
    const float lsep = mp + __logf(redA[0]);
    const float lseq = mq + __logf(redB[0]);
    __syncthreads();

    // pass 3: JSD
    float accj = 0.f;
    for (int i = tid; i < VOC / 8; i += 1024) {
        s16x8 vt = *(const s16x8*)(tl + i * 8);
        s16x8 vs = *(const s16x8*)(sl + i * 8);
        #pragma unroll
        for (int j = 0; j < 8; ++j) {
            float lp = bf2f((unsigned short)vt[j]) - lsep;   // teacher log-prob
            float lq = bf2f((unsigned short)vs[j]) - lseq;   // student log-prob
            float m0 = fmaxf(lp, lq);
            float lm = m0 + __logf(0.5f * (__expf(lp - m0) + __expf(lq - m0)));
            accj += 0.5f * (__expf(lp) * (lp - lm) + __expf(lq) * (lq - lm));
        }
    }
    #pragma unroll
    for (int o = 32; o > 0; o >>= 1) accj += __shfl_xor(accj, o);
    if ((tid & 63) == 0) redA[tid >> 6] = accj;
    __syncthreads();
    if (tid == 0) {
        float a = 0.f;
        for (int w = 0; w < 16; ++w) a += redA[w];
        if (label[b] != IGN) atomicAdd(out, a * invn[0]);
    }
}

extern "C" void kernel_launch(void* const* d_in, const int* in_sizes, int n_in,
                              void* d_out, int out_size, void* d_ws, size_t ws_size,
                              hipStream_t stream) {
    const float* s_in = (const float*)d_in[0];   // [BT, 2048]
    const float* t_in = (const float*)d_in[1];   // [BT, 4096]
    const float* Ws   = (const float*)d_in[2];   // [VOC, 2048]
    const float* Wt   = (const float*)d_in[3];   // [VOC, 4096]
    const int* label  = (const int*)d_in[4];     // [BT]
    float* out = (float*)d_out;

    const size_t logitsElems = (size_t)BT * VOC;
    const size_t need = logitsElems * 2 * sizeof(unsigned short) + 64;
    if (ws_size < need) return;  // would fail visibly (poisoned d_out)

    unsigned short* logT = (unsigned short*)d_ws;
    unsigned short* logS = logT + logitsElems;
    float* invn = (float*)(logS + logitsElems);

    count_kernel<<<dim3(1), dim3(256), 0, stream>>>(label, invn, out);
    gemm_bf16<<<dim3(16 * (VOC / 128)), dim3(256), 0, stream>>>(t_in, Wt, logT, 4096);
    gemm_bf16<<<dim3(16 * (VOC / 128)), dim3(256), 0, stream>>>(s_in, Ws, logS, 2048);
    jsd_kernel<<<dim3(BT), dim3(1024), 0, stream>>>(logT, logS, label, invn, out);
}

// Round 2
// 1292.609 us; speedup vs baseline: 1.2466x; 1.2466x over previous
//
#include <hip/hip_runtime.h>
#include <hip/hip_bf16.h>

#define BT 2048
#define VOC 32000
#define IGN (-100)

typedef __attribute__((ext_vector_type(4))) float f32x4;
typedef __attribute__((ext_vector_type(8))) short s16x8;
typedef __attribute__((ext_vector_type(4))) unsigned int u32x4;

__device__ __forceinline__ unsigned short f2bf(float f) {
    union { __hip_bfloat16 h; unsigned short u; } c;
    c.h = __float2bfloat16(f);
    return c.u;
}
__device__ __forceinline__ float bf2f(unsigned short u) {
    union { unsigned int u; float f; } c;
    c.u = ((unsigned int)u) << 16;
    return c.f;
}
__device__ __forceinline__ unsigned int pk2(float a, float b) {
    return (unsigned int)f2bf(a) | ((unsigned int)f2bf(b) << 16);
}

// ---------------------------------------------------------------------------
// fp32 -> bf16 pre-convert (memory-bound, 16B in / 16B... 32B in, 16B out per iter)
// ---------------------------------------------------------------------------
__global__ __launch_bounds__(256)
void cvt_kernel(const float* __restrict__ in, unsigned short* __restrict__ out, int n8) {
    for (int i = blockIdx.x * 256 + threadIdx.x; i < n8; i += gridDim.x * 256) {
        f32x4 a = ((const f32x4*)in)[2 * i];
        f32x4 b = ((const f32x4*)in)[2 * i + 1];
        u32x4 o;
        o[0] = pk2(a[0], a[1]);
        o[1] = pk2(a[2], a[3]);
        o[2] = pk2(b[0], b[1]);
        o[3] = pk2(b[2], b[3]);
        ((u32x4*)out)[i] = o;
    }
}

// ---------------------------------------------------------------------------
// GEMM (bf16 operands): C[m,v] = sum_k A[m,k] * W[v,k]
// 128x128 tile, BK=64, 256 thr (4 waves 2x2), mfma_f32_16x16x32_bf16.
// Pipeline: raw s_barrier (no vmcnt drain) + 2 reg staging sets:
//   step t: issue loads(t+2); compute(t) from LDS[t&1]; write regs(t+1)->LDS[(t+1)&1];
//           lgkmcnt(0); s_barrier.
// XOR-swizzled LDS (granule ^= row&7) -> 0 bank conflicts (verified round 1).
// XCD swizzle: 16 m-tiles sharing a W-tile land on one XCD's L2.
// ---------------------------------------------------------------------------
#define LOADSET(sa, sb, step) do {                                            \
    const int kb_ = (step) << 6;                                              \
    _Pragma("unroll")                                                         \
    for (int it = 0; it < 4; ++it) {                                          \
        sa[it] = *(const u32x4*)(Ab + (size_t)rrow[it] * K + kb_ + rg[it] * 8); \
        sb[it] = *(const u32x4*)(Wb + (size_t)rrow[it] * K + kb_ + rg[it] * 8); \
    } } while (0)

#define WRITESET(sa, sb, buf) do {                                            \
    _Pragma("unroll")                                                         \
    for (int it = 0; it < 4; ++it) {                                          \
        const int off_ = rrow[it] * 64 + ((rg[it] ^ (rrow[it] & 7)) * 8);     \
        *(u32x4*)&lds[buf][0][off_] = sa[it];                                 \
        *(u32x4*)&lds[buf][1][off_] = sb[it];                                 \
    } } while (0)

#define LGKM0_BARRIER() do {                                                  \
    asm volatile("s_waitcnt lgkmcnt(0)" ::: "memory");                        \
    __builtin_amdgcn_s_barrier();                                             \
    asm volatile("" ::: "memory");                                            \
    } while (0)

__global__ __launch_bounds__(256, 2)
void gemm_bb(const unsigned short* __restrict__ A, const unsigned short* __restrict__ W,
             unsigned short* __restrict__ C, int K) {
    const int cpx = gridDim.x >> 3;
    const int braw = blockIdx.x;
    const int bid = (braw & 7) * cpx + (braw >> 3);   // bijective: gridDim % 8 == 0
    const int mt = bid & 15;
    const int nt = bid >> 4;
    const int tid = threadIdx.x;
    const int lane = tid & 63;
    const int wave = tid >> 6;
    const int wm = (wave >> 1) << 6;
    const int wn = (wave & 1) << 6;

    __shared__ unsigned short lds[2][2][128 * 64];

    f32x4 acc[4][4];
    #pragma unroll
    for (int m = 0; m < 4; ++m)
        #pragma unroll
        for (int n = 0; n < 4; ++n)
            acc[m][n] = (f32x4){0.f, 0.f, 0.f, 0.f};

    const unsigned short* Ab = A + (size_t)(mt * 128) * K;
    const unsigned short* Wb = W + (size_t)(nt * 128) * K;
    const int nsteps = K >> 6;

    int rrow[4], rg[4];
    #pragma unroll
    for (int it = 0; it < 4; ++it) {
        int idx = it * 256 + tid;    // 1024 granules of 16B per operand-tile
        rrow[it] = idx >> 3;
        rg[it] = idx & 7;
    }

    u32x4 sa0[4], sb0[4], sa1[4], sb1[4];

    auto compute = [&](int buf) {
        #pragma unroll
        for (int ks = 0; ks < 2; ++ks) {
            const int g = ks * 4 + (lane >> 4);
            const int rsel = lane & 15;
            s16x8 af[4], bw[4];
            #pragma unroll
            for (int m = 0; m < 4; ++m) {
                int row = wm + m * 16 + rsel;
                af[m] = *(const s16x8*)&lds[buf][0][row * 64 + ((g ^ (row & 7)) * 8)];
            }
            #pragma unroll
            for (int n = 0; n < 4; ++n) {
                int row = wn + n * 16 + rsel;
                bw[n] = *(const s16x8*)&lds[buf][1][row * 64 + ((g ^ (row & 7)) * 8)];
            }
            #pragma unroll
            for (int m = 0; m < 4; ++m)
                #pragma unroll
                for (int n = 0; n < 4; ++n)
                    acc[m][n] = __builtin_amdgcn_mfma_f32_16x16x32_bf16(
                        af[m], bw[n], acc[m][n], 0, 0, 0);
        }
    };

    // prologue: issue tiles 0 and 1; stage tile 0 to LDS[0]
    LOADSET(sa0, sb0, 0);
    LOADSET(sa1, sb1, 1);
    WRITESET(sa0, sb0, 0);            // compiler waits only set0's loads (vmcnt(8))
    LGKM0_BARRIER();

    for (int t = 0; t < nsteps; t += 2) {
        // even step: compute tile t from LDS[0]; stage tile t+1 (set1) -> LDS[1]
        if (t + 2 < nsteps) LOADSET(sa0, sb0, t + 2);
        compute(0);
        WRITESET(sa1, sb1, 1);
        LGKM0_BARRIER();
        // odd step: compute tile t+1 from LDS[1]; stage tile t+2 (set0) -> LDS[0]
        if (t + 3 < nsteps) LOADSET(sa1, sb1, t + 3);
        compute(1);
        if (t + 2 < nsteps) {
            WRITESET(sa0, sb0, 0);
        }
        LGKM0_BARRIER();
    }

    // epilogue: C/D layout col = lane&15, row = (lane>>4)*4 + reg
    const int colb = nt * 128 + wn + (lane & 15);
    const int rowb = mt * 128 + wm + ((lane >> 4) << 2);
    #pragma unroll
    for (int m = 0; m < 4; ++m)
        #pragma unroll
        for (int n = 0; n < 4; ++n) {
            #pragma unroll
            for (int j = 0; j < 4; ++j) {
                int r = rowb + m * 16 + j;
                int c = colb + n * 16;
                C[(size_t)r * VOC + c] = f2bf(acc[m][n][j]);
            }
        }
}

// ---------------------------------------------------------------------------
// Fallback GEMM (fp32 operands, reg-staged convert) — round-1 verified path,
// used only if ws is too small for bf16 operand copies.
// ---------------------------------------------------------------------------
__global__ __launch_bounds__(256, 2)
void gemm_bf16(const float* __restrict__ A, const float* __restrict__ W,
               unsigned short* __restrict__ C, int K) {
    const int bid = blockIdx.x;
    const int mt = bid & 15;
    const int nt = bid >> 4;
    const int tid = threadIdx.x;
    const int lane = tid & 63;
    const int wave = tid >> 6;
    const int wm = (wave >> 1) << 6;
    const int wn = (wave & 1) << 6;

    __shared__ unsigned short lds[2][2][128 * 64];

    f32x4 acc[4][4];
    #pragma unroll
    for (int m = 0; m < 4; ++m)
        #pragma unroll
        for (int n = 0; n < 4; ++n)
            acc[m][n] = (f32x4){0.f, 0.f, 0.f, 0.f};

    const float* Ab = A + (size_t)(mt * 128) * K;
    const float* Wb = W + (size_t)(nt * 128) * K;
    const int nsteps = K >> 6;

    f32x4 ra[4][2], rb[4][2];
    int rrow[4], rk16[4];
    #pragma unroll
    for (int it = 0; it < 4; ++it) {
        int idx = it * 256 + tid;
        rrow[it] = idx >> 3;
        rk16[it] = idx & 7;
    }

    auto load_regs = [&](int step) {
        const int kb = step << 6;
        #pragma unroll
        for (int it = 0; it < 4; ++it) {
            const float* pa = Ab + (size_t)rrow[it] * K + kb + rk16[it] * 8;
            const float* pw = Wb + (size_t)rrow[it] * K + kb + rk16[it] * 8;
            ra[it][0] = *(const f32x4*)pa;
            ra[it][1] = *(const f32x4*)(pa + 4);
            rb[it][0] = *(const f32x4*)pw;
            rb[it][1] = *(const f32x4*)(pw + 4);
        }
    };

    auto write_lds = [&](int buf) {
        #pragma unroll
        for (int it = 0; it < 4; ++it) {
            const int row = rrow[it];
            const int sw = rk16[it] ^ (row & 7);
            const int off = row * 64 + sw * 8;
            u32x4 pa, pw;
            pa[0] = pk2(ra[it][0][0], ra[it][0][1]);
            pa[1] = pk2(ra[it][0][2], ra[it][0][3]);
            pa[2] = pk2(ra[it][1][0], ra[it][1][1]);
            pa[3] = pk2(ra[it][1][2], ra[it][1][3]);
            pw[0] = pk2(rb[it][0][0], rb[it][0][1]);
            pw[1] = pk2(rb[it][0][2], rb[it][0][3]);
            pw[2] = pk2(rb[it][1][0], rb[it][1][1]);
            pw[3] = pk2(rb[it][1][2], rb[it][1][3]);
            *(u32x4*)&lds[buf][0][off] = pa;
            *(u32x4*)&lds[buf][1][off] = pw;
        }
    };

    auto compute = [&](int buf) {
        #pragma unroll
        for (int ks = 0; ks < 2; ++ks) {
            const int g = ks * 4 + (lane >> 4);
            const int rsel = lane & 15;
            s16x8 af[4], bw[4];
            #pragma unroll
            for (int m = 0; m < 4; ++m) {
                int row = wm + m * 16 + rsel;
                af[m] = *(const s16x8*)&lds[buf][0][row * 64 + ((g ^ (row & 7)) * 8)];
            }
            #pragma unroll
            for (int n = 0; n < 4; ++n) {
                int row = wn + n * 16 + rsel;
                bw[n] = *(const s16x8*)&lds[buf][1][row * 64 + ((g ^ (row & 7)) * 8)];
            }
            #pragma unroll
            for (int m = 0; m < 4; ++m)
                #pragma unroll
                for (int n = 0; n < 4; ++n)
                    acc[m][n] = __builtin_amdgcn_mfma_f32_16x16x32_bf16(
                        af[m], bw[n], acc[m][n], 0, 0, 0);
        }
    };

    load_regs(0);
    write_lds(0);
    __syncthreads();
    for (int s = 0; s < nsteps; ++s) {
        if (s + 1 < nsteps) load_regs(s + 1);
        compute(s & 1);
        if (s + 1 < nsteps) write_lds((s + 1) & 1);
        __syncthreads();
    }

    const int colb = nt * 128 + wn + (lane & 15);
    const int rowb = mt * 128 + wm + ((lane >> 4) << 2);
    #pragma unroll
    for (int m = 0; m < 4; ++m)
        #pragma unroll
        for (int n = 0; n < 4; ++n) {
            #pragma unroll
            for (int j = 0; j < 4; ++j) {
                int r = rowb + m * 16 + j;
                int c = colb + n * 16;
                C[(size_t)r * VOC + c] = f2bf(acc[m][n][j]);
            }
        }
}

// ---------------------------------------------------------------------------
// count kernel: n_non_ignore -> 1/n (or 0), and zero d_out (graph-replay safe)
// ---------------------------------------------------------------------------
__global__ void count_kernel(const int* __restrict__ label,
                             float* __restrict__ invn, float* __restrict__ out) {
    int tid = threadIdx.x;
    int c = 0;
    for (int i = tid; i < BT; i += 256) c += (label[i] != IGN) ? 1 : 0;
    #pragma unroll
    for (int o = 32; o > 0; o >>= 1) c += __shfl_xor(c, o);
    __shared__ int red[4];
    if ((tid & 63) == 0) red[tid >> 6] = c;
    __syncthreads();
    if (tid == 0) {
        int n = red[0] + red[1] + red[2] + red[3];
        invn[0] = (n > 0) ? (1.0f / (float)n) : 0.0f;
        out[0] = 0.0f;
    }
}

// ---------------------------------------------------------------------------
// JSD kernel: one block per token, 3 passes over both bf16 logit rows.
// ---------------------------------------------------------------------------
__global__ __launch_bounds__(1024)
void jsd_kernel(const unsigned short* __restrict__ TL, const unsigned short* __restrict__ SL,
                const int* __restrict__ label, const float* __restrict__ invn,
                float* __restrict__ out) {
    const int b = blockIdx.x;
    const int tid = threadIdx.x;
    const unsigned short* tl = TL + (size_t)b * VOC;
    const unsigned short* sl = SL + (size_t)b * VOC;
    __shared__ float redA[16], redB[16];

    float mp = -1e30f, mq = -1e30f;
    for (int i = tid; i < VOC / 8; i += 1024) {
        s16x8 vt = *(const s16x8*)(tl + i * 8);
        s16x8 vs = *(const s16x8*)(sl + i * 8);
        #pragma unroll
        for (int j = 0; j < 8; ++j) {
            mp = fmaxf(mp, bf2f((unsigned short)vt[j]));
            mq = fmaxf(mq, bf2f((unsigned short)vs[j]));
        }
    }
    #pragma unroll
    for (int o = 32; o > 0; o >>= 1) {
        mp = fmaxf(mp, __shfl_xor(mp, o));
        mq = fmaxf(mq, __shfl_xor(mq, o));
    }
    if ((tid & 63) == 0) { redA[tid >> 6] = mp; redB[tid >> 6] = mq; }
    __syncthreads();
    if (tid == 0) {
        float a = redA[0], c = redB[0];
        for (int w = 1; w < 16; ++w) { a = fmaxf(a, redA[w]); c = fmaxf(c, redB[w]); }
        redA[0] = a; redB[0] = c;
    }
    __syncthreads();
    mp = redA[0]; mq = redB[0];
    __syncthreads();

    float sp = 0.f, sq = 0.f;
    for (int i = tid; i < VOC / 8; i += 1024) {
        s16x8 vt = *(const s16x8*)(tl + i * 8);
        s16x8 vs = *(const s16x8*)(sl + i * 8);
        #pragma unroll
        for (int j = 0; j < 8; ++j) {
            sp += __expf(bf2f((unsigned short)vt[j]) - mp);
            sq += __expf(bf2f((unsigned short)vs[j]) - mq);
        }
    }
    #pragma unroll
    for (int o = 32; o > 0; o >>= 1) {
        sp += __shfl_xor(sp, o);
        sq += __shfl_xor(sq, o);
    }
    if ((tid & 63) == 0) { redA[tid >> 6] = sp; redB[tid >> 6] = sq; }
    __syncthreads();
    if (tid == 0) {
        float a = 0.f, c = 0.f;
        for (int w = 0; w < 16; ++w) { a += redA[w]; c += redB[w]; }
        redA[0] = a; redB[0] = c;
    }
    __syncthreads();
    const float lsep = mp + __logf(redA[0]);
    const float lseq = mq + __logf(redB[0]);
    __syncthreads();

    float accj = 0.f;
    for (int i = tid; i < VOC / 8; i += 1024) {
        s16x8 vt = *(const s16x8*)(tl + i * 8);
        s16x8 vs = *(const s16x8*)(sl + i * 8);
        #pragma unroll
        for (int j = 0; j < 8; ++j) {
            float lp = bf2f((unsigned short)vt[j]) - lsep;
            float lq = bf2f((unsigned short)vs[j]) - lseq;
            float m0 = fmaxf(lp, lq);
            float lm = m0 + __logf(0.5f * (__expf(lp - m0) + __expf(lq - m0)));
            accj += 0.5f * (__expf(lp) * (lp - lm) + __expf(lq) * (lq - lm));
        }
    }
    #pragma unroll
    for (int o = 32; o > 0; o >>= 1) accj += __shfl_xor(accj, o);
    if ((tid & 63) == 0) redA[tid >> 6] = accj;
    __syncthreads();
    if (tid == 0) {
        float a = 0.f;
        for (int w = 0; w < 16; ++w) a += redA[w];
        if (label[b] != IGN) atomicAdd(out, a * invn[0]);
    }
}

extern "C" void kernel_launch(void* const* d_in, const int* in_sizes, int n_in,
                              void* d_out, int out_size, void* d_ws, size_t ws_size,
                              hipStream_t stream) {
    const float* s_in = (const float*)d_in[0];   // [BT, 2048]
    const float* t_in = (const float*)d_in[1];   // [BT, 4096]
    const float* Ws   = (const float*)d_in[2];   // [VOC, 2048]
    const float* Wt   = (const float*)d_in[3];   // [VOC, 4096]
    const int* label  = (const int*)d_in[4];     // [BT]
    float* out = (float*)d_out;

    const size_t L   = (size_t)BT * VOC;
    const size_t eWt = (size_t)VOC * 4096;
    const size_t eWs = (size_t)VOC * 2048;
    const size_t eAt = (size_t)BT * 4096;
    const size_t eAs = (size_t)BT * 2048;

    const size_t need_full = (2 * L + eWt + eWs + eAt + eAs) * sizeof(unsigned short) + 64;
    const size_t need_min  = 2 * L * sizeof(unsigned short) + 64;

    if (ws_size >= need_full) {
        unsigned short* logT = (unsigned short*)d_ws;
        unsigned short* logS = logT + L;
        unsigned short* Wtb  = logS + L;
        unsigned short* Wsb  = Wtb + eWt;
        unsigned short* Atb  = Wsb + eWs;
        unsigned short* Asb  = Atb + eAt;
        float* invn = (float*)(Asb + eAs);

        cvt_kernel<<<dim3(2048), dim3(256), 0, stream>>>(Wt, Wtb, (int)(eWt / 8));
        cvt_kernel<<<dim3(2048), dim3(256), 0, stream>>>(Ws, Wsb, (int)(eWs / 8));
        cvt_kernel<<<dim3(1024), dim3(256), 0, stream>>>(t_in, Atb, (int)(eAt / 8));
        cvt_kernel<<<dim3(1024), dim3(256), 0, stream>>>(s_in, Asb, (int)(eAs / 8));
        count_kernel<<<dim3(1), dim3(256), 0, stream>>>(label, invn, out);
        gemm_bb<<<dim3(16 * (VOC / 128)), dim3(256), 0, stream>>>(Atb, Wtb, logT, 4096);
        gemm_bb<<<dim3(16 * (VOC / 128)), dim3(256), 0, stream>>>(Asb, Wsb, logS, 2048);
        jsd_kernel<<<dim3(BT), dim3(1024), 0, stream>>>(logT, logS, label, invn, out);
    } else {
        if (ws_size < need_min) return;
        unsigned short* logT = (unsigned short*)d_ws;
        unsigned short* logS = logT + L;
        float* invn = (float*)(logS + L);

        count_kernel<<<dim3(1), dim3(256), 0, stream>>>(label, invn, out);
        gemm_bf16<<<dim3(16 * (VOC / 128)), dim3(256), 0, stream>>>(t_in, Wt, logT, 4096);
        gemm_bf16<<<dim3(16 * (VOC / 128)), dim3(256), 0, stream>>>(s_in, Ws, logS, 2048);
        jsd_kernel<<<dim3(BT), dim3(1024), 0, stream>>>(logT, logS, label, invn, out);
    }
}

// Round 3
// 1244.854 us; speedup vs baseline: 1.2944x; 1.0384x over previous
//
#include <hip/hip_runtime.h>
#include <hip/hip_bf16.h>

#define BT 2048
#define VOC 32000
#define IGN (-100)

typedef __attribute__((ext_vector_type(4))) float f32x4;
typedef __attribute__((ext_vector_type(8))) short s16x8;
typedef __attribute__((ext_vector_type(4))) unsigned int u32x4;

#define AS1 __attribute__((address_space(1)))
#define AS3 __attribute__((address_space(3)))

__device__ __forceinline__ unsigned short f2bf(float f) {
    union { __hip_bfloat16 h; unsigned short u; } c;
    c.h = __float2bfloat16(f);
    return c.u;
}
__device__ __forceinline__ float bf2f(unsigned short u) {
    union { unsigned int u; float f; } c;
    c.u = ((unsigned int)u) << 16;
    return c.f;
}
__device__ __forceinline__ unsigned int pk2(float a, float b) {
    return (unsigned int)f2bf(a) | ((unsigned int)f2bf(b) << 16);
}

// ---------------------------------------------------------------------------
// fp32 -> bf16 pre-convert (memory-bound)
// ---------------------------------------------------------------------------
__global__ __launch_bounds__(256)
void cvt_kernel(const float* __restrict__ in, unsigned short* __restrict__ out, int n8) {
    for (int i = blockIdx.x * 256 + threadIdx.x; i < n8; i += gridDim.x * 256) {
        f32x4 a = ((const f32x4*)in)[2 * i];
        f32x4 b = ((const f32x4*)in)[2 * i + 1];
        u32x4 o;
        o[0] = pk2(a[0], a[1]);
        o[1] = pk2(a[2], a[3]);
        o[2] = pk2(b[0], b[1]);
        o[3] = pk2(b[2], b[3]);
        ((u32x4*)out)[i] = o;
    }
}

// ---------------------------------------------------------------------------
// 8-phase 256x256 GEMM (bf16 operands): C[m,v] = sum_k A[m,k] * W[v,k]
// BK=64, 512 thr (8 waves, 2Mx4N), per-wave 128x64 out, mfma 16x16x32_bf16.
// global_load_lds direct staging: linear LDS dest + inverse-swizzled global
// source; ds_read applies the same XOR swizzle (granule ^= row&7).
// Stage schedule per K-tile u (each region provably dead before its write):
//   phase1 (quad 0,0): issue A1(u+1)   phase2 (0,1): issue B1(u+1)
//   phase3 (1,0):      issue A0(u+2)   phase4 (1,1): issue B0(u+2) + vmcnt(4)
// vmcnt(4) at tile end => tile u+1 fully landed, 2 half-tiles stay in flight.
// Tail (u+2 >= nsteps): vmcnt(0) since A1/B1(u+1) are the newest ops.
// ---------------------------------------------------------------------------
#define FENCE() asm volatile("" ::: "memory")
#define BARRIER() do { FENCE(); __builtin_amdgcn_s_barrier(); FENCE(); } while (0)
#define WAIT_LGKM0() do { asm volatile("s_waitcnt lgkmcnt(0)" ::: "memory"); \
                          __builtin_amdgcn_sched_barrier(0); } while (0)

#define STAGE(arr, base, h, t, b) do { if ((t) < nsteps) {                    \
    _Pragma("unroll")                                                         \
    for (int l_ = 0; l_ < 2; ++l_) {                                          \
        const int gi_ = (wave * 2 + l_) * 64 + lane;                          \
        const int r_ = gi_ >> 3, gp_ = gi_ & 7;                               \
        const unsigned short* src_ = (base) + (size_t)((h) * 128 + r_) * K    \
                  + ((size_t)(t) << 6) + ((gp_ ^ (r_ & 7)) << 3);             \
        unsigned short* dst_ =                                                \
            (unsigned short*)&(arr)[b][(h) * 8192 + (wave * 2 + l_) * 512];   \
        __builtin_amdgcn_global_load_lds((AS1 const void*)src_,               \
                                         (AS3 void*)dst_, 16, 0, 0);          \
    } } } while (0)

#define RD_A(mh, b) do {                                                      \
    _Pragma("unroll") for (int m_ = 0; m_ < 4; ++m_)                          \
    _Pragma("unroll") for (int ks_ = 0; ks_ < 2; ++ks_) {                     \
        const int row_ = wr * 128 + (mh) * 64 + m_ * 16 + (lane & 15);        \
        const int g_ = ks_ * 4 + (lane >> 4);                                 \
        af[m_][ks_] = *(const s16x8*)&lA[b][row_ * 64 + ((g_ ^ (row_ & 7)) << 3)]; \
    } } while (0)

#define RD_B(nh, b) do {                                                      \
    _Pragma("unroll") for (int n_ = 0; n_ < 2; ++n_)                          \
    _Pragma("unroll") for (int ks_ = 0; ks_ < 2; ++ks_) {                     \
        const int row_ = wc * 64 + (nh) * 32 + n_ * 16 + (lane & 15);         \
        const int g_ = ks_ * 4 + (lane >> 4);                                 \
        bw[n_][ks_] = *(const s16x8*)&lB[b][row_ * 64 + ((g_ ^ (row_ & 7)) << 3)]; \
    } } while (0)

#define MM(mh, nh) do {                                                       \
    __builtin_amdgcn_s_setprio(1);                                            \
    _Pragma("unroll") for (int m_ = 0; m_ < 4; ++m_)                          \
    _Pragma("unroll") for (int n_ = 0; n_ < 2; ++n_)                          \
    _Pragma("unroll") for (int ks_ = 0; ks_ < 2; ++ks_)                       \
        acc[(mh) * 4 + m_][(nh) * 2 + n_] =                                   \
            __builtin_amdgcn_mfma_f32_16x16x32_bf16(                          \
                af[m_][ks_], bw[n_][ks_], acc[(mh) * 4 + m_][(nh) * 2 + n_],  \
                0, 0, 0);                                                     \
    __builtin_amdgcn_s_setprio(0);                                            \
} while (0)

__global__ __launch_bounds__(512, 2)
void gemm8p(const unsigned short* __restrict__ A, const unsigned short* __restrict__ W,
            unsigned short* __restrict__ C, int K) {
    const int cpx = gridDim.x >> 3;
    const int braw = blockIdx.x;
    const int bid = (braw & 7) * cpx + (braw >> 3);   // bijective: grid % 8 == 0
    const int mt = bid & 7;       // 2048/256 = 8 row tiles (m-inner: W-tile reuse)
    const int nt = bid >> 3;      // 0..124
    const int tid = threadIdx.x;
    const int lane = tid & 63;
    const int wave = tid >> 6;
    const int wr = wave >> 2;     // 0..1
    const int wc = wave & 3;      // 0..3

    __shared__ unsigned short lA[2][16384];   // [buf][256 rows x 64 bf16] (2 halves)
    __shared__ unsigned short lB[2][16384];

    f32x4 acc[8][4];
    #pragma unroll
    for (int m = 0; m < 8; ++m)
        #pragma unroll
        for (int n = 0; n < 4; ++n)
            acc[m][n] = (f32x4){0.f, 0.f, 0.f, 0.f};

    const unsigned short* Ab = A + (size_t)(mt * 256) * K;
    const unsigned short* Wb = W + (size_t)(nt * 256) * K;
    const int nsteps = K >> 6;

    s16x8 af[4][2];
    s16x8 bw[2][2];

    // prologue: tile0 (4 half-tiles) + A0,B0 of tile1; tile0 landed after vmcnt(4)
    STAGE(lA, Ab, 0, 0, 0); STAGE(lB, Wb, 0, 0, 0);
    STAGE(lA, Ab, 1, 0, 0); STAGE(lB, Wb, 1, 0, 0);
    STAGE(lA, Ab, 0, 1, 1); STAGE(lB, Wb, 0, 1, 1);
    asm volatile("s_waitcnt vmcnt(4)" ::: "memory");
    BARRIER();

    for (int u = 0; u < nsteps; ++u) {
        const int b_ = u & 1;
        // phase 1: quadrant (0,0)
        RD_A(0, b_); RD_B(0, b_);
        STAGE(lA, Ab, 1, u + 1, (u + 1) & 1);
        BARRIER();
        WAIT_LGKM0();
        MM(0, 0);
        BARRIER();
        // phase 2: quadrant (0,1) — reuse af
        RD_B(1, b_);
        STAGE(lB, Wb, 1, u + 1, (u + 1) & 1);
        BARRIER();
        WAIT_LGKM0();
        MM(0, 1);
        BARRIER();
        // phase 3: quadrant (1,0)
        RD_A(1, b_); RD_B(0, b_);
        STAGE(lA, Ab, 0, u + 2, b_);
        BARRIER();
        WAIT_LGKM0();
        MM(1, 0);
        BARRIER();
        // phase 4: quadrant (1,1)
        RD_B(1, b_);
        STAGE(lB, Wb, 0, u + 2, b_);
        BARRIER();
        WAIT_LGKM0();
        MM(1, 1);
        if (u + 2 < nsteps) asm volatile("s_waitcnt vmcnt(4)" ::: "memory");
        else                asm volatile("s_waitcnt vmcnt(0)" ::: "memory");
        BARRIER();
    }

    // epilogue: C/D layout col = lane&15, row = (lane>>4)*4 + reg
    const int colb = nt * 256 + wc * 64 + (lane & 15);
    const int rowb = mt * 256 + wr * 128 + ((lane >> 4) << 2);
    #pragma unroll
    for (int m = 0; m < 8; ++m)
        #pragma unroll
        for (int n = 0; n < 4; ++n) {
            #pragma unroll
            for (int j = 0; j < 4; ++j) {
                const size_t r = (size_t)(rowb + m * 16 + j);
                C[r * VOC + colb + n * 16] = f2bf(acc[m][n][j]);
            }
        }
}

// ---------------------------------------------------------------------------
// Fallback GEMM (fp32 operands, reg-staged convert) — used only if ws too small.
// ---------------------------------------------------------------------------
__global__ __launch_bounds__(256, 2)
void gemm_bf16(const float* __restrict__ A, const float* __restrict__ W,
               unsigned short* __restrict__ C, int K) {
    const int bid = blockIdx.x;
    const int mt = bid & 15;
    const int nt = bid >> 4;
    const int tid = threadIdx.x;
    const int lane = tid & 63;
    const int wave = tid >> 6;
    const int wm = (wave >> 1) << 6;
    const int wn = (wave & 1) << 6;

    __shared__ unsigned short lds[2][2][128 * 64];

    f32x4 acc[4][4];
    #pragma unroll
    for (int m = 0; m < 4; ++m)
        #pragma unroll
        for (int n = 0; n < 4; ++n)
            acc[m][n] = (f32x4){0.f, 0.f, 0.f, 0.f};

    const float* Ab = A + (size_t)(mt * 128) * K;
    const float* Wb = W + (size_t)(nt * 128) * K;
    const int nsteps = K >> 6;

    f32x4 ra[4][2], rb[4][2];
    int rrow[4], rk16[4];
    #pragma unroll
    for (int it = 0; it < 4; ++it) {
        int idx = it * 256 + tid;
        rrow[it] = idx >> 3;
        rk16[it] = idx & 7;
    }

    auto load_regs = [&](int step) {
        const int kb = step << 6;
        #pragma unroll
        for (int it = 0; it < 4; ++it) {
            const float* pa = Ab + (size_t)rrow[it] * K + kb + rk16[it] * 8;
            const float* pw = Wb + (size_t)rrow[it] * K + kb + rk16[it] * 8;
            ra[it][0] = *(const f32x4*)pa;
            ra[it][1] = *(const f32x4*)(pa + 4);
            rb[it][0] = *(const f32x4*)pw;
            rb[it][1] = *(const f32x4*)(pw + 4);
        }
    };

    auto write_lds = [&](int buf) {
        #pragma unroll
        for (int it = 0; it < 4; ++it) {
            const int row = rrow[it];
            const int sw = rk16[it] ^ (row & 7);
            const int off = row * 64 + sw * 8;
            u32x4 pa, pw;
            pa[0] = pk2(ra[it][0][0], ra[it][0][1]);
            pa[1] = pk2(ra[it][0][2], ra[it][0][3]);
            pa[2] = pk2(ra[it][1][0], ra[it][1][1]);
            pa[3] = pk2(ra[it][1][2], ra[it][1][3]);
            pw[0] = pk2(rb[it][0][0], rb[it][0][1]);
            pw[1] = pk2(rb[it][0][2], rb[it][0][3]);
            pw[2] = pk2(rb[it][1][0], rb[it][1][1]);
            pw[3] = pk2(rb[it][1][2], rb[it][1][3]);
            *(u32x4*)&lds[buf][0][off] = pa;
            *(u32x4*)&lds[buf][1][off] = pw;
        }
    };

    auto compute = [&](int buf) {
        #pragma unroll
        for (int ks = 0; ks < 2; ++ks) {
            const int g = ks * 4 + (lane >> 4);
            const int rsel = lane & 15;
            s16x8 afr[4], bwr[4];
            #pragma unroll
            for (int m = 0; m < 4; ++m) {
                int row = wm + m * 16 + rsel;
                afr[m] = *(const s16x8*)&lds[buf][0][row * 64 + ((g ^ (row & 7)) * 8)];
            }
            #pragma unroll
            for (int n = 0; n < 4; ++n) {
                int row = wn + n * 16 + rsel;
                bwr[n] = *(const s16x8*)&lds[buf][1][row * 64 + ((g ^ (row & 7)) * 8)];
            }
            #pragma unroll
            for (int m = 0; m < 4; ++m)
                #pragma unroll
                for (int n = 0; n < 4; ++n)
                    acc[m][n] = __builtin_amdgcn_mfma_f32_16x16x32_bf16(
                        afr[m], bwr[n], acc[m][n], 0, 0, 0);
        }
    };

    load_regs(0);
    write_lds(0);
    __syncthreads();
    for (int s = 0; s < nsteps; ++s) {
        if (s + 1 < nsteps) load_regs(s + 1);
        compute(s & 1);
        if (s + 1 < nsteps) write_lds((s + 1) & 1);
        __syncthreads();
    }

    const int colb = nt * 128 + wn + (lane & 15);
    const int rowb = mt * 128 + wm + ((lane >> 4) << 2);
    #pragma unroll
    for (int m = 0; m < 4; ++m)
        #pragma unroll
        for (int n = 0; n < 4; ++n) {
            #pragma unroll
            for (int j = 0; j < 4; ++j) {
                int r = rowb + m * 16 + j;
                int c = colb + n * 16;
                C[(size_t)r * VOC + c] = f2bf(acc[m][n][j]);
            }
        }
}

// ---------------------------------------------------------------------------
// count kernel: n_non_ignore -> 1/n (or 0), and zero d_out (graph-replay safe)
// ---------------------------------------------------------------------------
__global__ void count_kernel(const int* __restrict__ label,
                             float* __restrict__ invn, float* __restrict__ out) {
    int tid = threadIdx.x;
    int c = 0;
    for (int i = tid; i < BT; i += 256) c += (label[i] != IGN) ? 1 : 0;
    #pragma unroll
    for (int o = 32; o > 0; o >>= 1) c += __shfl_xor(c, o);
    __shared__ int red[4];
    if ((tid & 63) == 0) red[tid >> 6] = c;
    __syncthreads();
    if (tid == 0) {
        int n = red[0] + red[1] + red[2] + red[3];
        invn[0] = (n > 0) ? (1.0f / (float)n) : 0.0f;
        out[0] = 0.0f;
    }
}

// ---------------------------------------------------------------------------
// JSD kernel: one block per token, 3 passes over both bf16 logit rows.
// ---------------------------------------------------------------------------
__global__ __launch_bounds__(1024)
void jsd_kernel(const unsigned short* __restrict__ TL, const unsigned short* __restrict__ SL,
                const int* __restrict__ label, const float* __restrict__ invn,
                float* __restrict__ out) {
    const int b = blockIdx.x;
    const int tid = threadIdx.x;
    const unsigned short* tl = TL + (size_t)b * VOC;
    const unsigned short* sl = SL + (size_t)b * VOC;
    __shared__ float redA[16], redB[16];

    float mp = -1e30f, mq = -1e30f;
    for (int i = tid; i < VOC / 8; i += 1024) {
        s16x8 vt = *(const s16x8*)(tl + i * 8);
        s16x8 vs = *(const s16x8*)(sl + i * 8);
        #pragma unroll
        for (int j = 0; j < 8; ++j) {
            mp = fmaxf(mp, bf2f((unsigned short)vt[j]));
            mq = fmaxf(mq, bf2f((unsigned short)vs[j]));
        }
    }
    #pragma unroll
    for (int o = 32; o > 0; o >>= 1) {
        mp = fmaxf(mp, __shfl_xor(mp, o));
        mq = fmaxf(mq, __shfl_xor(mq, o));
    }
    if ((tid & 63) == 0) { redA[tid >> 6] = mp; redB[tid >> 6] = mq; }
    __syncthreads();
    if (tid == 0) {
        float a = redA[0], c = redB[0];
        for (int w = 1; w < 16; ++w) { a = fmaxf(a, redA[w]); c = fmaxf(c, redB[w]); }
        redA[0] = a; redB[0] = c;
    }
    __syncthreads();
    mp = redA[0]; mq = redB[0];
    __syncthreads();

    float sp = 0.f, sq = 0.f;
    for (int i = tid; i < VOC / 8; i += 1024) {
        s16x8 vt = *(const s16x8*)(tl + i * 8);
        s16x8 vs = *(const s16x8*)(sl + i * 8);
        #pragma unroll
        for (int j = 0; j < 8; ++j) {
            sp += __expf(bf2f((unsigned short)vt[j]) - mp);
            sq += __expf(bf2f((unsigned short)vs[j]) - mq);
        }
    }
    #pragma unroll
    for (int o = 32; o > 0; o >>= 1) {
        sp += __shfl_xor(sp, o);
        sq += __shfl_xor(sq, o);
    }
    if ((tid & 63) == 0) { redA[tid >> 6] = sp; redB[tid >> 6] = sq; }
    __syncthreads();
    if (tid == 0) {
        float a = 0.f, c = 0.f;
        for (int w = 0; w < 16; ++w) { a += redA[w]; c += redB[w]; }
        redA[0] = a; redB[0] = c;
    }
    __syncthreads();
    const float lsep = mp + __logf(redA[0]);
    const float lseq = mq + __logf(redB[0]);
    __syncthreads();

    float accj = 0.f;
    for (int i = tid; i < VOC / 8; i += 1024) {
        s16x8 vt = *(const s16x8*)(tl + i * 8);
        s16x8 vs = *(const s16x8*)(sl + i * 8);
        #pragma unroll
        for (int j = 0; j < 8; ++j) {
            float lp = bf2f((unsigned short)vt[j]) - lsep;
            float lq = bf2f((unsigned short)vs[j]) - lseq;
            float m0 = fmaxf(lp, lq);
            float lm = m0 + __logf(0.5f * (__expf(lp - m0) + __expf(lq - m0)));
            accj += 0.5f * (__expf(lp) * (lp - lm) + __expf(lq) * (lq - lm));
        }
    }
    #pragma unroll
    for (int o = 32; o > 0; o >>= 1) accj += __shfl_xor(accj, o);
    if ((tid & 63) == 0) redA[tid >> 6] = accj;
    __syncthreads();
    if (tid == 0) {
        float a = 0.f;
        for (int w = 0; w < 16; ++w) a += redA[w];
        if (label[b] != IGN) atomicAdd(out, a * invn[0]);
    }
}

extern "C" void kernel_launch(void* const* d_in, const int* in_sizes, int n_in,
                              void* d_out, int out_size, void* d_ws, size_t ws_size,
                              hipStream_t stream) {
    const float* s_in = (const float*)d_in[0];   // [BT, 2048]
    const float* t_in = (const float*)d_in[1];   // [BT, 4096]
    const float* Ws   = (const float*)d_in[2];   // [VOC, 2048]
    const float* Wt   = (const float*)d_in[3];   // [VOC, 4096]
    const int* label  = (const int*)d_in[4];     // [BT]
    float* out = (float*)d_out;

    const size_t L   = (size_t)BT * VOC;
    const size_t eWt = (size_t)VOC * 4096;
    const size_t eWs = (size_t)VOC * 2048;
    const size_t eAt = (size_t)BT * 4096;
    const size_t eAs = (size_t)BT * 2048;

    const size_t need_full = (2 * L + eWt + eWs + eAt + eAs) * sizeof(unsigned short) + 64;
    const size_t need_min  = 2 * L * sizeof(unsigned short) + 64;

    if (ws_size >= need_full) {
        unsigned short* logT = (unsigned short*)d_ws;
        unsigned short* logS = logT + L;
        unsigned short* Wtb  = logS + L;
        unsigned short* Wsb  = Wtb + eWt;
        unsigned short* Atb  = Wsb + eWs;
        unsigned short* Asb  = Atb + eAt;
        float* invn = (float*)(Asb + eAs);

        cvt_kernel<<<dim3(2048), dim3(256), 0, stream>>>(Wt, Wtb, (int)(eWt / 8));
        cvt_kernel<<<dim3(2048), dim3(256), 0, stream>>>(Ws, Wsb, (int)(eWs / 8));
        cvt_kernel<<<dim3(1024), dim3(256), 0, stream>>>(t_in, Atb, (int)(eAt / 8));
        cvt_kernel<<<dim3(1024), dim3(256), 0, stream>>>(s_in, Asb, (int)(eAs / 8));
        count_kernel<<<dim3(1), dim3(256), 0, stream>>>(label, invn, out);
        gemm8p<<<dim3(8 * (VOC / 256)), dim3(512), 0, stream>>>(Atb, Wtb, logT, 4096);
        gemm8p<<<dim3(8 * (VOC / 256)), dim3(512), 0, stream>>>(Asb, Wsb, logS, 2048);
        jsd_kernel<<<dim3(BT), dim3(1024), 0, stream>>>(logT, logS, label, invn, out);
    } else {
        if (ws_size < need_min) return;
        unsigned short* logT = (unsigned short*)d_ws;
        unsigned short* logS = logT + L;
        float* invn = (float*)(logS + L);

        count_kernel<<<dim3(1), dim3(256), 0, stream>>>(label, invn, out);
        gemm_bf16<<<dim3(16 * (VOC / 128)), dim3(256), 0, stream>>>(t_in, Wt, logT, 4096);
        gemm_bf16<<<dim3(16 * (VOC / 128)), dim3(256), 0, stream>>>(s_in, Ws, logS, 2048);
        jsd_kernel<<<dim3(BT), dim3(1024), 0, stream>>>(logT, logS, label, invn, out);
    }
}

// Round 4
// 1123.946 us; speedup vs baseline: 1.4337x; 1.1076x over previous
//
#include <hip/hip_runtime.h>
#include <hip/hip_bf16.h>

#define BT 2048
#define VOC 32000
#define IGN (-100)

typedef __attribute__((ext_vector_type(4))) float f32x4;
typedef __attribute__((ext_vector_type(8))) short s16x8;
typedef __attribute__((ext_vector_type(4))) unsigned int u32x4;

#define AS1 __attribute__((address_space(1)))
#define AS3 __attribute__((address_space(3)))

__device__ __forceinline__ unsigned short f2bf(float f) {
    union { __hip_bfloat16 h; unsigned short u; } c;
    c.h = __float2bfloat16(f);
    return c.u;
}
__device__ __forceinline__ float bf2f(unsigned short u) {
    union { unsigned int u; float f; } c;
    c.u = ((unsigned int)u) << 16;
    return c.f;
}
__device__ __forceinline__ unsigned int pk2(float a, float b) {
    return (unsigned int)f2bf(a) | ((unsigned int)f2bf(b) << 16);
}

// ---------------------------------------------------------------------------
// fp32 -> bf16 pre-convert (memory-bound)
// ---------------------------------------------------------------------------
__global__ __launch_bounds__(256)
void cvt_kernel(const float* __restrict__ in, unsigned short* __restrict__ out, int n8) {
    for (int i = blockIdx.x * 256 + threadIdx.x; i < n8; i += gridDim.x * 256) {
        f32x4 a = ((const f32x4*)in)[2 * i];
        f32x4 b = ((const f32x4*)in)[2 * i + 1];
        u32x4 o;
        o[0] = pk2(a[0], a[1]);
        o[1] = pk2(a[2], a[3]);
        o[2] = pk2(b[0], b[1]);
        o[3] = pk2(b[2], b[3]);
        ((u32x4*)out)[i] = o;
    }
}

// ---------------------------------------------------------------------------
// 256x256 GEMM (bf16 operands), 4-region K-half ring, 1 barrier per phase.
// C[m,v] = sum_k A[m,k] * W[v,k].  BK=64 split in 2 K-halves (one 16x16x32
// k-step each).  512 thr (8 waves 2Mx4N), per-wave 128x64 out.
//
// Regions r=0..3 (= [buf][khalf]); each holds A: 256rows x 32k and
// B: 256rows x 32k as [128 row-pairs][64] with XOR swizzle
// (granule position sgi = ((row&1)*4 + k_gran) ^ (rowpair&7)) -> 2-way max.
// Staged via global_load_lds (linear LDS dest, inverse-swizzled global src).
//
// Phase p (=2t+kh) : consume region p%4; stage region (p+2)%4 (dead >= 2
// barriers -> no LDS write/read race); per-wave lgkmcnt(0) only (no
// mid-phase barrier -> cross-wave LDS/MFMA overlap); vmcnt(4) + s_barrier
// at phase end (keeps the 4 gloads of this phase in flight across it).
// Reads: 12 ds_read_b128 per wave per phase (B read once per tile).
// ---------------------------------------------------------------------------
#define FENCE() asm volatile("" ::: "memory")
#define BARRIER() do { FENCE(); __builtin_amdgcn_s_barrier(); FENCE(); } while (0)
#define WAIT_LGKM0() do { asm volatile("s_waitcnt lgkmcnt(0)" ::: "memory"); \
                          __builtin_amdgcn_sched_barrier(0); } while (0)

#define STAGEH(larr, Base, kh, t, r) do { if ((t) < nsteps) {                 \
    _Pragma("unroll")                                                         \
    for (int l_ = 0; l_ < 2; ++l_) {                                          \
        const int gi_ = (wave * 2 + l_) * 64 + lane;                          \
        const int rp_ = gi_ >> 3, sgi_ = gi_ & 7;                             \
        const int raw_ = sgi_ ^ (rp_ & 7);                                    \
        const int row_ = rp_ * 2 + (raw_ >> 2);                               \
        const int gk_ = raw_ & 3;                                             \
        const unsigned short* src_ = (Base) + (size_t)row_ * K                \
                  + ((size_t)(t) << 6) + (kh) * 32 + gk_ * 8;                 \
        unsigned short* dst_ = (unsigned short*)&(larr)[r][(wave * 2 + l_) * 512]; \
        __builtin_amdgcn_global_load_lds((AS1 const void*)src_,               \
                                         (AS3 void*)dst_, 16, 0, 0);          \
    } } } while (0)

__global__ __launch_bounds__(512, 2)
void gemm2p(const unsigned short* __restrict__ A, const unsigned short* __restrict__ W,
            unsigned short* __restrict__ C, int K) {
    const int cpx = gridDim.x >> 3;
    const int braw = blockIdx.x;
    const int bid = (braw & 7) * cpx + (braw >> 3);   // bijective: grid % 8 == 0
    const int mt = bid & 7;       // 2048/256 = 8 row tiles (m-inner: W-panel reuse)
    const int nt = bid >> 3;      // 0..124
    const int tid = threadIdx.x;
    const int lane = tid & 63;
    const int wave = tid >> 6;
    const int wr = wave >> 2;     // 0..1
    const int wc = wave & 3;      // 0..3

    __shared__ unsigned short lA[4][8192];   // 4 regions: 256 rows x 32 k each
    __shared__ unsigned short lB[4][8192];

    f32x4 acc[8][4];
    #pragma unroll
    for (int m = 0; m < 8; ++m)
        #pragma unroll
        for (int n = 0; n < 4; ++n)
            acc[m][n] = (f32x4){0.f, 0.f, 0.f, 0.f};

    const unsigned short* Ab = A + (size_t)(mt * 256) * K;
    const unsigned short* Wb = W + (size_t)(nt * 256) * K;
    const int nsteps = K >> 6;

    // prologue: stage tile0 k-half0 -> R0, k-half1 -> R1; R0 landed at vmcnt(4)
    STAGEH(lA, Ab, 0, 0, 0); STAGEH(lB, Wb, 0, 0, 0);
    STAGEH(lA, Ab, 1, 0, 1); STAGEH(lB, Wb, 1, 0, 1);
    asm volatile("s_waitcnt vmcnt(4)" ::: "memory");
    BARRIER();

    for (int t = 0; t < nsteps; ++t) {
        #pragma unroll
        for (int kh = 0; kh < 2; ++kh) {
            const int r = ((t & 1) << 1) | kh;
            // ds-read this phase's fragments (one k-step) from region r
            s16x8 a[8], b[4];
            #pragma unroll
            for (int mf = 0; mf < 8; ++mf) {
                const int row = wr * 128 + mf * 16 + (lane & 15);
                const int raw = (row & 1) * 4 + (lane >> 4);
                const int rp = row >> 1;
                a[mf] = *(const s16x8*)&lA[r][rp * 64 + ((raw ^ (rp & 7)) << 3)];
            }
            #pragma unroll
            for (int nf = 0; nf < 4; ++nf) {
                const int row = wc * 64 + nf * 16 + (lane & 15);
                const int raw = (row & 1) * 4 + (lane >> 4);
                const int rp = row >> 1;
                b[nf] = *(const s16x8*)&lB[r][rp * 64 + ((raw ^ (rp & 7)) << 3)];
            }
            // stage tile t+1, same k-half, into region (r+2)&3 (dead region)
            STAGEH(lA, Ab, kh, t + 1, (r + 2) & 3);
            STAGEH(lB, Wb, kh, t + 1, (r + 2) & 3);
            // own-reads done -> MFMA burst (waves drift; LDS/MFMA overlap)
            WAIT_LGKM0();
            __builtin_amdgcn_s_setprio(1);
            #pragma unroll
            for (int mf = 0; mf < 8; ++mf)
                #pragma unroll
                for (int nf = 0; nf < 4; ++nf)
                    acc[mf][nf] = __builtin_amdgcn_mfma_f32_16x16x32_bf16(
                        a[mf], b[nf], acc[mf][nf], 0, 0, 0);
            __builtin_amdgcn_s_setprio(0);
            // next phase's region must have landed; keep this phase's 4 in flight
            if (t + 1 < nsteps) asm volatile("s_waitcnt vmcnt(4)" ::: "memory");
            else                asm volatile("s_waitcnt vmcnt(0)" ::: "memory");
            BARRIER();
        }
    }

    // epilogue: C/D layout col = lane&15, row = (lane>>4)*4 + reg
    const int colb = nt * 256 + wc * 64 + (lane & 15);
    const int rowb = mt * 256 + wr * 128 + ((lane >> 4) << 2);
    #pragma unroll
    for (int m = 0; m < 8; ++m)
        #pragma unroll
        for (int n = 0; n < 4; ++n) {
            #pragma unroll
            for (int j = 0; j < 4; ++j) {
                const size_t r = (size_t)(rowb + m * 16 + j);
                C[r * VOC + colb + n * 16] = f2bf(acc[m][n][j]);
            }
        }
}

// ---------------------------------------------------------------------------
// Fallback GEMM (fp32 operands, reg-staged convert) — used only if ws too small.
// ---------------------------------------------------------------------------
__global__ __launch_bounds__(256, 2)
void gemm_bf16(const float* __restrict__ A, const float* __restrict__ W,
               unsigned short* __restrict__ C, int K) {
    const int bid = blockIdx.x;
    const int mt = bid & 15;
    const int nt = bid >> 4;
    const int tid = threadIdx.x;
    const int lane = tid & 63;
    const int wave = tid >> 6;
    const int wm = (wave >> 1) << 6;
    const int wn = (wave & 1) << 6;

    __shared__ unsigned short lds[2][2][128 * 64];

    f32x4 acc[4][4];
    #pragma unroll
    for (int m = 0; m < 4; ++m)
        #pragma unroll
        for (int n = 0; n < 4; ++n)
            acc[m][n] = (f32x4){0.f, 0.f, 0.f, 0.f};

    const float* Ab = A + (size_t)(mt * 128) * K;
    const float* Wb = W + (size_t)(nt * 128) * K;
    const int nsteps = K >> 6;

    f32x4 ra[4][2], rb[4][2];
    int rrow[4], rk16[4];
    #pragma unroll
    for (int it = 0; it < 4; ++it) {
        int idx = it * 256 + tid;
        rrow[it] = idx >> 3;
        rk16[it] = idx & 7;
    }

    auto load_regs = [&](int step) {
        const int kb = step << 6;
        #pragma unroll
        for (int it = 0; it < 4; ++it) {
            const float* pa = Ab + (size_t)rrow[it] * K + kb + rk16[it] * 8;
            const float* pw = Wb + (size_t)rrow[it] * K + kb + rk16[it] * 8;
            ra[it][0] = *(const f32x4*)pa;
            ra[it][1] = *(const f32x4*)(pa + 4);
            rb[it][0] = *(const f32x4*)pw;
            rb[it][1] = *(const f32x4*)(pw + 4);
        }
    };

    auto write_lds = [&](int buf) {
        #pragma unroll
        for (int it = 0; it < 4; ++it) {
            const int row = rrow[it];
            const int sw = rk16[it] ^ (row & 7);
            const int off = row * 64 + sw * 8;
            u32x4 pa, pw;
            pa[0] = pk2(ra[it][0][0], ra[it][0][1]);
            pa[1] = pk2(ra[it][0][2], ra[it][0][3]);
            pa[2] = pk2(ra[it][1][0], ra[it][1][1]);
            pa[3] = pk2(ra[it][1][2], ra[it][1][3]);
            pw[0] = pk2(rb[it][0][0], rb[it][0][1]);
            pw[1] = pk2(rb[it][0][2], rb[it][0][3]);
            pw[2] = pk2(rb[it][1][0], rb[it][1][1]);
            pw[3] = pk2(rb[it][1][2], rb[it][1][3]);
            *(u32x4*)&lds[buf][0][off] = pa;
            *(u32x4*)&lds[buf][1][off] = pw;
        }
    };

    auto compute = [&](int buf) {
        #pragma unroll
        for (int ks = 0; ks < 2; ++ks) {
            const int g = ks * 4 + (lane >> 4);
            const int rsel = lane & 15;
            s16x8 afr[4], bwr[4];
            #pragma unroll
            for (int m = 0; m < 4; ++m) {
                int row = wm + m * 16 + rsel;
                afr[m] = *(const s16x8*)&lds[buf][0][row * 64 + ((g ^ (row & 7)) * 8)];
            }
            #pragma unroll
            for (int n = 0; n < 4; ++n) {
                int row = wn + n * 16 + rsel;
                bwr[n] = *(const s16x8*)&lds[buf][1][row * 64 + ((g ^ (row & 7)) * 8)];
            }
            #pragma unroll
            for (int m = 0; m < 4; ++m)
                #pragma unroll
                for (int n = 0; n < 4; ++n)
                    acc[m][n] = __builtin_amdgcn_mfma_f32_16x16x32_bf16(
                        afr[m], bwr[n], acc[m][n], 0, 0, 0);
        }
    };

    load_regs(0);
    write_lds(0);
    __syncthreads();
    for (int s = 0; s < nsteps; ++s) {
        if (s + 1 < nsteps) load_regs(s + 1);
        compute(s & 1);
        if (s + 1 < nsteps) write_lds((s + 1) & 1);
        __syncthreads();
    }

    const int colb = nt * 128 + wn + (lane & 15);
    const int rowb = mt * 128 + wm + ((lane >> 4) << 2);
    #pragma unroll
    for (int m = 0; m < 4; ++m)
        #pragma unroll
        for (int n = 0; n < 4; ++n) {
            #pragma unroll
            for (int j = 0; j < 4; ++j) {
                int r = rowb + m * 16 + j;
                int c = colb + n * 16;
                C[(size_t)r * VOC + c] = f2bf(acc[m][n][j]);
            }
        }
}

// ---------------------------------------------------------------------------
// count kernel: n_non_ignore -> 1/n (or 0), and zero d_out (graph-replay safe)
// ---------------------------------------------------------------------------
__global__ void count_kernel(const int* __restrict__ label,
                             float* __restrict__ invn, float* __restrict__ out) {
    int tid = threadIdx.x;
    int c = 0;
    for (int i = tid; i < BT; i += 256) c += (label[i] != IGN) ? 1 : 0;
    #pragma unroll
    for (int o = 32; o > 0; o >>= 1) c += __shfl_xor(c, o);
    __shared__ int red[4];
    if ((tid & 63) == 0) red[tid >> 6] = c;
    __syncthreads();
    if (tid == 0) {
        int n = red[0] + red[1] + red[2] + red[3];
        invn[0] = (n > 0) ? (1.0f / (float)n) : 0.0f;
        out[0] = 0.0f;
    }
}

// ---------------------------------------------------------------------------
// JSD kernel: one block per token, 3 passes over both bf16 logit rows.
// ---------------------------------------------------------------------------
__global__ __launch_bounds__(1024)
void jsd_kernel(const unsigned short* __restrict__ TL, const unsigned short* __restrict__ SL,
                const int* __restrict__ label, const float* __restrict__ invn,
                float* __restrict__ out) {
    const int b = blockIdx.x;
    const int tid = threadIdx.x;
    const unsigned short* tl = TL + (size_t)b * VOC;
    const unsigned short* sl = SL + (size_t)b * VOC;
    __shared__ float redA[16], redB[16];

    float mp = -1e30f, mq = -1e30f;
    for (int i = tid; i < VOC / 8; i += 1024) {
        s16x8 vt = *(const s16x8*)(tl + i * 8);
        s16x8 vs = *(const s16x8*)(sl + i * 8);
        #pragma unroll
        for (int j = 0; j < 8; ++j) {
            mp = fmaxf(mp, bf2f((unsigned short)vt[j]));
            mq = fmaxf(mq, bf2f((unsigned short)vs[j]));
        }
    }
    #pragma unroll
    for (int o = 32; o > 0; o >>= 1) {
        mp = fmaxf(mp, __shfl_xor(mp, o));
        mq = fmaxf(mq, __shfl_xor(mq, o));
    }
    if ((tid & 63) == 0) { redA[tid >> 6] = mp; redB[tid >> 6] = mq; }
    __syncthreads();
    if (tid == 0) {
        float a = redA[0], c = redB[0];
        for (int w = 1; w < 16; ++w) { a = fmaxf(a, redA[w]); c = fmaxf(c, redB[w]); }
        redA[0] = a; redB[0] = c;
    }
    __syncthreads();
    mp = redA[0]; mq = redB[0];
    __syncthreads();

    float sp = 0.f, sq = 0.f;
    for (int i = tid; i < VOC / 8; i += 1024) {
        s16x8 vt = *(const s16x8*)(tl + i * 8);
        s16x8 vs = *(const s16x8*)(sl + i * 8);
        #pragma unroll
        for (int j = 0; j < 8; ++j) {
            sp += __expf(bf2f((unsigned short)vt[j]) - mp);
            sq += __expf(bf2f((unsigned short)vs[j]) - mq);
        }
    }
    #pragma unroll
    for (int o = 32; o > 0; o >>= 1) {
        sp += __shfl_xor(sp, o);
        sq += __shfl_xor(sq, o);
    }
    if ((tid & 63) == 0) { redA[tid >> 6] = sp; redB[tid >> 6] = sq; }
    __syncthreads();
    if (tid == 0) {
        float a = 0.f, c = 0.f;
        for (int w = 0; w < 16; ++w) { a += redA[w]; c += redB[w]; }
        redA[0] = a; redB[0] = c;
    }
    __syncthreads();
    const float lsep = mp + __logf(redA[0]);
    const float lseq = mq + __logf(redB[0]);
    __syncthreads();

    float accj = 0.f;
    for (int i = tid; i < VOC / 8; i += 1024) {
        s16x8 vt = *(const s16x8*)(tl + i * 8);
        s16x8 vs = *(const s16x8*)(sl + i * 8);
        #pragma unroll
        for (int j = 0; j < 8; ++j) {
            float lp = bf2f((unsigned short)vt[j]) - lsep;
            float lq = bf2f((unsigned short)vs[j]) - lseq;
            float m0 = fmaxf(lp, lq);
            float lm = m0 + __logf(0.5f * (__expf(lp - m0) + __expf(lq - m0)));
            accj += 0.5f * (__expf(lp) * (lp - lm) + __expf(lq) * (lq - lm));
        }
    }
    #pragma unroll
    for (int o = 32; o > 0; o >>= 1) accj += __shfl_xor(accj, o);
    if ((tid & 63) == 0) redA[tid >> 6] = accj;
    __syncthreads();
    if (tid == 0) {
        float a = 0.f;
        for (int w = 0; w < 16; ++w) a += redA[w];
        if (label[b] != IGN) atomicAdd(out, a * invn[0]);
    }
}

extern "C" void kernel_launch(void* const* d_in, const int* in_sizes, int n_in,
                              void* d_out, int out_size, void* d_ws, size_t ws_size,
                              hipStream_t stream) {
    const float* s_in = (const float*)d_in[0];   // [BT, 2048]
    const float* t_in = (const float*)d_in[1];   // [BT, 4096]
    const float* Ws   = (const float*)d_in[2];   // [VOC, 2048]
    const float* Wt   = (const float*)d_in[3];   // [VOC, 4096]
    const int* label  = (const int*)d_in[4];     // [BT]
    float* out = (float*)d_out;

    const size_t L   = (size_t)BT * VOC;
    const size_t eWt = (size_t)VOC * 4096;
    const size_t eWs = (size_t)VOC * 2048;
    const size_t eAt = (size_t)BT * 4096;
    const size_t eAs = (size_t)BT * 2048;

    const size_t need_full = (2 * L + eWt + eWs + eAt + eAs) * sizeof(unsigned short) + 64;
    const size_t need_min  = 2 * L * sizeof(unsigned short) + 64;

    if (ws_size >= need_full) {
        unsigned short* logT = (unsigned short*)d_ws;
        unsigned short* logS = logT + L;
        unsigned short* Wtb  = logS + L;
        unsigned short* Wsb  = Wtb + eWt;
        unsigned short* Atb  = Wsb + eWs;
        unsigned short* Asb  = Atb + eAt;
        float* invn = (float*)(Asb + eAs);

        cvt_kernel<<<dim3(2048), dim3(256), 0, stream>>>(Wt, Wtb, (int)(eWt / 8));
        cvt_kernel<<<dim3(2048), dim3(256), 0, stream>>>(Ws, Wsb, (int)(eWs / 8));
        cvt_kernel<<<dim3(1024), dim3(256), 0, stream>>>(t_in, Atb, (int)(eAt / 8));
        cvt_kernel<<<dim3(1024), dim3(256), 0, stream>>>(s_in, Asb, (int)(eAs / 8));
        count_kernel<<<dim3(1), dim3(256), 0, stream>>>(label, invn, out);
        gemm2p<<<dim3(8 * (VOC / 256)), dim3(512), 0, stream>>>(Atb, Wtb, logT, 4096);
        gemm2p<<<dim3(8 * (VOC / 256)), dim3(512), 0, stream>>>(Asb, Wsb, logS, 2048);
        jsd_kernel<<<dim3(BT), dim3(1024), 0, stream>>>(logT, logS, label, invn, out);
    } else {
        if (ws_size < need_min) return;
        unsigned short* logT = (unsigned short*)d_ws;
        unsigned short* logS = logT + L;
        float* invn = (float*)(logS + L);

        count_kernel<<<dim3(1), dim3(256), 0, stream>>>(label, invn, out);
        gemm_bf16<<<dim3(16 * (VOC / 128)), dim3(256), 0, stream>>>(t_in, Wt, logT, 4096);
        gemm_bf16<<<dim3(16 * (VOC / 128)), dim3(256), 0, stream>>>(s_in, Ws, logS, 2048);
        jsd_kernel<<<dim3(BT), dim3(1024), 0, stream>>>(logT, logS, label, invn, out);
    }
}